// Round 1
// 271.837 us; speedup vs baseline: 1.1186x; 1.1186x over previous
//
#include <hip/hip_runtime.h>

#define BB 64
#define HH 128
#define CC 1024
#define QQ 128

typedef unsigned short u16;
typedef unsigned int u32;
using bf16x8 = __attribute__((ext_vector_type(8))) short;
using f32x4 = __attribute__((ext_vector_type(4))) float;

#define MFMA16(a, b, c) __builtin_amdgcn_mfma_f32_16x16x32_bf16(a, b, c, 0, 0, 0)

__device__ __forceinline__ float lo2f(u32 u) {
  union { float f; u32 i; } v; v.i = u << 16; return v.f;
}
__device__ __forceinline__ float hi2f(u32 u) {
  union { float f; u32 i; } v; v.i = u & 0xFFFF0000u; return v.f;
}
__device__ __forceinline__ u16 f2b(float f) {
  union { float f; u32 i; } v; v.f = f;
  u32 r = v.i + 0x7FFFu + ((v.i >> 16) & 1u);   // RNE
  return (u16)(r >> 16);
}
// hi = truncate-to-bf16(x); lo = truncate-to-bf16(x - hi).  x = hi+lo+eps,
// |eps| <= 2^-16 |x|  (Dekker split; exact subtraction since hi has 8 mantissa bits)
__device__ __forceinline__ u32 pack_hi2(float a, float b) {
  return (__float_as_uint(a) >> 16) | (__float_as_uint(b) & 0xFFFF0000u);
}
__device__ __forceinline__ u32 pack_lo2(float a, float b) {
  float ra = a - __uint_as_float(__float_as_uint(a) & 0xFFFF0000u);
  float rb = b - __uint_as_float(__float_as_uint(b) & 0xFFFF0000u);
  return (__float_as_uint(ra) >> 16) | (__float_as_uint(rb) & 0xFFFF0000u);
}

// stage 16 consecutive fp32 into LDS as 16 hi-bf16 + 16 lo-bf16.
__device__ __forceinline__ void stage16(const float* __restrict__ p,
                                        u16* dhi, u16* dlo) {
  float4 a0 = *(const float4*)p;
  float4 a1 = *(const float4*)(p + 4);
  float4 a2 = *(const float4*)(p + 8);
  float4 a3 = *(const float4*)(p + 12);
  uint4 h0 = {pack_hi2(a0.x, a0.y), pack_hi2(a0.z, a0.w),
              pack_hi2(a1.x, a1.y), pack_hi2(a1.z, a1.w)};
  uint4 h1 = {pack_hi2(a2.x, a2.y), pack_hi2(a2.z, a2.w),
              pack_hi2(a3.x, a3.y), pack_hi2(a3.z, a3.w)};
  uint4 l0 = {pack_lo2(a0.x, a0.y), pack_lo2(a0.z, a0.w),
              pack_lo2(a1.x, a1.y), pack_lo2(a1.z, a1.w)};
  uint4 l1 = {pack_lo2(a2.x, a2.y), pack_lo2(a2.z, a2.w),
              pack_lo2(a3.x, a3.y), pack_lo2(a3.z, a3.w)};
  *(uint4*)dhi = h0;
  *(uint4*)(dhi + 8) = h1;
  *(uint4*)dlo = l0;
  *(uint4*)(dlo + 8) = l1;
}

// ---------------------------------------------------------------------------
// K1: s[b,i,j] = cwc[i] + qwq[j] + sum_h c[i,h]*w_cq[h]*q[j,h], softmax over i
// per column j.  Writes s1 twice:
//   s1ws[b][j][i]        bf16  (A-operand for K2: rows j, K = i)
//   s1tb[b][jgrp][i][8]  bf16  (fragment-blocked transpose for K3's direct
//                               global A-frag loads: jgrp = j>>3)
// Grid (b, jgroup): blockIdx.x = b so the 8 j-blocks sharing ctx[b] land on
// the same XCD (linear id % 8 == b % 8) -> ctx read from L2, not HBM 8x.
// ---------------------------------------------------------------------------
__global__ __launch_bounds__(512) void k1_s_softmax(
    const float* __restrict__ ctx, const float* __restrict__ qst,
    const float* __restrict__ w, u16* __restrict__ s1ws,
    u16* __restrict__ s1tb) {
  const int b = blockIdx.x;
  const int j0 = blockIdx.y * 16;
  const int tid = threadIdx.x;
  const float* cb = ctx + (size_t)b * HH * CC;
  const float* qb = qst + (size_t)b * HH * QQ;

  float dotv[16][2];
  float qwq[16];
  float cwc[2] = {0.f, 0.f};
#pragma unroll
  for (int jj = 0; jj < 16; ++jj) {
    qwq[jj] = 0.f;
    dotv[jj][0] = dotv[jj][1] = 0.f;
  }

  for (int h = 0; h < HH; ++h) {
    const float2 cv = *(const float2*)(cb + (size_t)h * CC + tid * 2);
    float c0 = cv.x, c1 = cv.y;
    float wqv = w[h], wcv = w[HH + h], wcqv = w[2 * HH + h];
    cwc[0] += c0 * wcv; cwc[1] += c1 * wcv;
    float t0 = c0 * wcqv, t1 = c1 * wcqv;
    const float4* qrow = (const float4*)(qb + (size_t)h * QQ + j0);
    float4 q0 = qrow[0], q1 = qrow[1], q2 = qrow[2], q3 = qrow[3];
    float qv[16] = {q0.x, q0.y, q0.z, q0.w, q1.x, q1.y, q1.z, q1.w,
                    q2.x, q2.y, q2.z, q2.w, q3.x, q3.y, q3.z, q3.w};
#pragma unroll
    for (int jj = 0; jj < 16; ++jj) {
      qwq[jj] += qv[jj] * wqv;
      dotv[jj][0] += t0 * qv[jj];
      dotv[jj][1] += t1 * qv[jj];
    }
  }
#pragma unroll
  for (int jj = 0; jj < 16; ++jj) {
    float base = qwq[jj];
    dotv[jj][0] += cwc[0] + base;
    dotv[jj][1] += cwc[1] + base;
  }

  __shared__ float red[16 * 512];
  __shared__ float red2[16 * 32];
  __shared__ float bc[16];
  const int rj = tid >> 5, rs = tid & 31;

  // ---- max over i per column jj ----
#pragma unroll
  for (int jj = 0; jj < 16; ++jj)
    red[jj * 512 + tid] = fmaxf(dotv[jj][0], dotv[jj][1]);
  __syncthreads();
  {
    float m = red[rj * 512 + rs * 16];
#pragma unroll
    for (int g = 1; g < 16; ++g) m = fmaxf(m, red[rj * 512 + rs * 16 + g]);
    red2[rj * 32 + rs] = m;
  }
  __syncthreads();
  if (tid < 16) {
    float m = red2[tid * 32];
#pragma unroll
    for (int g = 1; g < 32; ++g) m = fmaxf(m, red2[tid * 32 + g]);
    bc[tid] = m;
  }
  __syncthreads();

  // ---- exp + sum ----
#pragma unroll
  for (int jj = 0; jj < 16; ++jj) {
    float mj = bc[jj];
    float e0 = __expf(dotv[jj][0] - mj);
    float e1 = __expf(dotv[jj][1] - mj);
    dotv[jj][0] = e0; dotv[jj][1] = e1;
    red[jj * 512 + tid] = e0 + e1;
  }
  __syncthreads();
  {
    float s = 0.f;
#pragma unroll
    for (int g = 0; g < 16; ++g) s += red[rj * 512 + rs * 16 + g];
    red2[rj * 32 + rs] = s;
  }
  __syncthreads();
  if (tid < 16) {
    float s = 0.f;
#pragma unroll
    for (int g = 0; g < 32; ++g) s += red2[tid * 32 + g];
    bc[tid] = 1.0f / s;
  }
  __syncthreads();

  // ---- normalize in place, then write both layouts ----
#pragma unroll
  for (int jj = 0; jj < 16; ++jj) {
    float inv = bc[jj];
    dotv[jj][0] *= inv;
    dotv[jj][1] *= inv;
  }
  u16* srow = s1ws + ((size_t)b * QQ + j0) * CC + tid * 2;
#pragma unroll
  for (int jj = 0; jj < 16; ++jj) {
    u32 pk = (u32)f2b(dotv[jj][0]) | ((u32)f2b(dotv[jj][1]) << 16);
    *(u32*)(srow + (size_t)jj * CC) = pk;
  }
  // blocked transpose: element (i, j) at s1tb[((j>>3)*1024 + i)*8 + (j&7)].
  // thread owns rows i = 2*tid, 2*tid+1 and jgroups j0/8, j0/8+1.
  u16* stb = s1tb + (size_t)b * (16 * 1024 * 8);
  const int jg0 = j0 >> 3;
#pragma unroll
  for (int g = 0; g < 2; ++g) {
#pragma unroll
    for (int rr = 0; rr < 2; ++rr) {
      const int o = g * 8;
      uint4 v;
      v.x = (u32)f2b(dotv[o + 0][rr]) | ((u32)f2b(dotv[o + 1][rr]) << 16);
      v.y = (u32)f2b(dotv[o + 2][rr]) | ((u32)f2b(dotv[o + 3][rr]) << 16);
      v.z = (u32)f2b(dotv[o + 4][rr]) | ((u32)f2b(dotv[o + 5][rr]) << 16);
      v.w = (u32)f2b(dotv[o + 6][rr]) | ((u32)f2b(dotv[o + 7][rr]) << 16);
      *(uint4*)(stb + ((size_t)(jg0 + g) * 1024 + (tid * 2 + rr)) * 8) = v;
    }
  }
}

// ---------------------------------------------------------------------------
// K2 (MFMA): tT[b][h][j] = t[j,h] = sum_i s1[i,j] c[i,h]
//          = mfma(A = ctx rows h (hi+lo bf16, LDS-staged),
//                 B = s1ws rows j (bf16, direct-global frags))
// Grid (b, kz=8): each block does K-slice of 128 i, 4 K-steps of 32.
// 4 waves x (h-quadrant 32 = 2 tiles) x (full j = 8 tiles). atomicAdd into tT
// (zeroed by hipMemsetAsync).
// ---------------------------------------------------------------------------
__global__ __launch_bounds__(256, 2) void k2_t(
    const float* __restrict__ ctx, const u16* __restrict__ s1ws,
    float* __restrict__ tT) {
  const int b = blockIdx.x;
  const int kz = blockIdx.y;
  const int tid = threadIdx.x;
  const int lane = tid & 63;
  const int wv = tid >> 6;
  const int l15 = lane & 15, l4 = lane >> 4;

  __shared__ u16 sHi[128 * 32];
  __shared__ u16 sLo[128 * 32];

  f32x4 acc[2][8];
#pragma unroll
  for (int ht = 0; ht < 2; ++ht)
#pragma unroll
    for (int jt = 0; jt < 8; ++jt) acc[ht][jt] = 0.f;

  const float* cb = ctx + (size_t)b * HH * CC;
  const u16* sb = s1ws + (size_t)b * QQ * CC;
  const int srow = tid >> 1;
  const int scol = (tid & 1) * 16;

  for (int ks = 0; ks < 4; ++ks) {
    const int ib = kz * 128 + ks * 32;
    __syncthreads();
    stage16(cb + (size_t)srow * CC + ib + scol,
            &sHi[srow * 32 + scol], &sLo[srow * 32 + scol]);
    __syncthreads();
    bf16x8 aHi[2], aLo[2];
#pragma unroll
    for (int ht = 0; ht < 2; ++ht) {
      const int ar = (wv * 32 + ht * 16 + l15) * 32 + l4 * 8;
      aHi[ht] = *(const bf16x8*)&sHi[ar];
      aLo[ht] = *(const bf16x8*)&sLo[ar];
    }
#pragma unroll
    for (int jt = 0; jt < 8; ++jt) {
      bf16x8 bf =
          *(const bf16x8*)(sb + (size_t)(jt * 16 + l15) * CC + ib + l4 * 8);
#pragma unroll
      for (int ht = 0; ht < 2; ++ht) {
        acc[ht][jt] = MFMA16(aHi[ht], bf, acc[ht][jt]);
        acc[ht][jt] = MFMA16(aLo[ht], bf, acc[ht][jt]);
      }
    }
  }
  // D layout: col = lane&15 (j), row = (lane>>4)*4 + reg (h)
  float* tb = tT + (size_t)b * HH * QQ;
#pragma unroll
  for (int ht = 0; ht < 2; ++ht)
#pragma unroll
    for (int jt = 0; jt < 8; ++jt)
#pragma unroll
      for (int r = 0; r < 4; ++r) {
        const int h = wv * 32 + ht * 16 + l4 * 4 + r;
        const int j = jt * 16 + l15;
        atomicAdd(&tb[(size_t)h * QQ + j], acc[ht][jt][r]);
      }
}

// ---------------------------------------------------------------------------
// K3 (MFMA): a[i,h] = sum_j s1[i,j] q[j,h];  bb[i,h] = sum_j s1[i,j] t[j,h]
//   A = s1tb blocked frags (bf16, direct-global; free = i, K = j)
//   B = qst[h][j] and tT[h][j] (hi+lo bf16, LDS-staged per 32-j slice)
// Grid (b, i-tile=8): block = 128 i x 128 h, 4 waves each h-quadrant 32.
// Epilogue fuses c / a / c*a / c*b sections of out.
// ---------------------------------------------------------------------------
__global__ __launch_bounds__(256, 2) void k3_out(
    const float* __restrict__ ctx, const float* __restrict__ qst,
    const u16* __restrict__ s1tb, const float* __restrict__ tT,
    float* __restrict__ out) {
  const int b = blockIdx.x;
  const int i0 = blockIdx.y * 128;
  const int tid = threadIdx.x;
  const int lane = tid & 63;
  const int wv = tid >> 6;
  const int l15 = lane & 15, l4 = lane >> 4;

  __shared__ u16 qHi[128 * 32], qLo[128 * 32];
  __shared__ u16 tHi[128 * 32], tLo[128 * 32];

  f32x4 accA[8][2], accB[8][2];
#pragma unroll
  for (int it = 0; it < 8; ++it)
#pragma unroll
    for (int ht = 0; ht < 2; ++ht) { accA[it][ht] = 0.f; accB[it][ht] = 0.f; }

  const u16* stb = s1tb + (size_t)b * (16 * 1024 * 8);
  const float* qb = qst + (size_t)b * HH * QQ;
  const float* tb = tT + (size_t)b * HH * QQ;
  const int srow = tid >> 1;
  const int scol = (tid & 1) * 16;

  for (int ks = 0; ks < 4; ++ks) {
    const int jb = ks * 32;
    __syncthreads();
    stage16(qb + (size_t)srow * QQ + jb + scol,
            &qHi[srow * 32 + scol], &qLo[srow * 32 + scol]);
    stage16(tb + (size_t)srow * QQ + jb + scol,
            &tHi[srow * 32 + scol], &tLo[srow * 32 + scol]);
    __syncthreads();
    bf16x8 qh[2], ql[2], th[2], tl[2];
#pragma unroll
    for (int ht = 0; ht < 2; ++ht) {
      const int ar = (wv * 32 + ht * 16 + l15) * 32 + l4 * 8;
      qh[ht] = *(const bf16x8*)&qHi[ar];
      ql[ht] = *(const bf16x8*)&qLo[ar];
      th[ht] = *(const bf16x8*)&tHi[ar];
      tl[ht] = *(const bf16x8*)&tLo[ar];
    }
    // A-frags direct from global (blocked layout), 2 halves to cap VGPRs.
#pragma unroll
    for (int half = 0; half < 2; ++half) {
      bf16x8 af[4];
#pragma unroll
      for (int t4 = 0; t4 < 4; ++t4) {
        const int it = half * 4 + t4;
        af[t4] = *(const bf16x8*)(stb +
            ((size_t)(ks * 4 + l4) * 1024 + i0 + it * 16 + l15) * 8);
      }
#pragma unroll
      for (int t4 = 0; t4 < 4; ++t4) {
        const int it = half * 4 + t4;
#pragma unroll
        for (int ht = 0; ht < 2; ++ht) {
          accA[it][ht] = MFMA16(af[t4], qh[ht], accA[it][ht]);
          accA[it][ht] = MFMA16(af[t4], ql[ht], accA[it][ht]);
          accB[it][ht] = MFMA16(af[t4], th[ht], accB[it][ht]);
          accB[it][ht] = MFMA16(af[t4], tl[ht], accB[it][ht]);
        }
      }
    }
  }

  // Epilogue: D col = lane&15 (h), rows = (lane>>4)*4 + reg (i).
  const float* cb = ctx + (size_t)b * HH * CC;
  float* ob = out + (size_t)b * 4 * HH * CC;
#pragma unroll
  for (int it = 0; it < 8; ++it)
#pragma unroll
    for (int ht = 0; ht < 2; ++ht) {
      const int h = wv * 32 + ht * 16 + l15;
      const int ii = i0 + it * 16 + l4 * 4;
      float4 cv = *(const float4*)(cb + (size_t)h * CC + ii);
      f32x4 aA = accA[it][ht], aB = accB[it][ht];
      float4 oA = {aA[0], aA[1], aA[2], aA[3]};
      float4 cA = {cv.x * oA.x, cv.y * oA.y, cv.z * oA.z, cv.w * oA.w};
      float4 cB = {cv.x * aB[0], cv.y * aB[1], cv.z * aB[2], cv.w * aB[3]};
      const size_t base = (size_t)h * CC + ii;
      *(float4*)(ob + base) = cv;
      *(float4*)(ob + (size_t)HH * CC + base) = oA;
      *(float4*)(ob + (size_t)2 * HH * CC + base) = cA;
      *(float4*)(ob + (size_t)3 * HH * CC + base) = cB;
    }
}

extern "C" void kernel_launch(void* const* d_in, const int* in_sizes, int n_in,
                              void* d_out, int out_size, void* d_ws, size_t ws_size,
                              hipStream_t stream) {
  const float* ctx = (const float*)d_in[0];
  const float* qst = (const float*)d_in[1];
  const float* w = (const float*)d_in[2];
  for (int k = 0; k < n_in; ++k) {
    if (in_sizes[k] == BB * HH * CC) ctx = (const float*)d_in[k];
    else if (in_sizes[k] == BB * HH * QQ) qst = (const float*)d_in[k];
    else if (in_sizes[k] == 3 * HH) w = (const float*)d_in[k];
  }
  float* out = (float*)d_out;

  // Workspace: s1ws bf16 (16 MiB) + s1tb bf16 (16 MiB) + tT fp32 (4 MiB).
  u16* s1ws = (u16*)d_ws;
  u16* s1tb = (u16*)((char*)d_ws + (size_t)16 * 1024 * 1024);
  float* tT = (float*)((char*)d_ws + (size_t)32 * 1024 * 1024);

  k1_s_softmax<<<dim3(BB, QQ / 16), 512, 0, stream>>>(ctx, qst, w, s1ws, s1tb);
  hipMemsetAsync(tT, 0, (size_t)BB * QQ * HH * sizeof(float), stream);
  k2_t<<<dim3(BB, 8), 256, 0, stream>>>(ctx, s1ws, tT);
  k3_out<<<dim3(BB, 8), 256, 0, stream>>>(ctx, qst, s1tb, tT, out);
}

// Round 3
// 250.935 us; speedup vs baseline: 1.2117x; 1.0833x over previous
//
#include <hip/hip_runtime.h>

#define BB 64
#define HH 128
#define CC 1024
#define QQ 128

typedef unsigned short u16;
typedef unsigned int u32;
using bf16x8 = __attribute__((ext_vector_type(8))) short;
using f32x4 = __attribute__((ext_vector_type(4))) float;

#define MFMA16(a, b, c) __builtin_amdgcn_mfma_f32_16x16x32_bf16(a, b, c, 0, 0, 0)

__device__ __forceinline__ float lo2f(u32 u) {
  union { float f; u32 i; } v; v.i = u << 16; return v.f;
}
__device__ __forceinline__ float hi2f(u32 u) {
  union { float f; u32 i; } v; v.i = u & 0xFFFF0000u; return v.f;
}
__device__ __forceinline__ u16 f2b(float f) {
  union { float f; u32 i; } v; v.f = f;
  u32 r = v.i + 0x7FFFu + ((v.i >> 16) & 1u);   // RNE
  return (u16)(r >> 16);
}
// Dekker hi/lo split packers: x = hi + lo + eps, |eps| <= 2^-16 |x|
__device__ __forceinline__ u32 pack_hi2(float a, float b) {
  return (__float_as_uint(a) >> 16) | (__float_as_uint(b) & 0xFFFF0000u);
}
__device__ __forceinline__ u32 pack_lo2(float a, float b) {
  float ra = a - __uint_as_float(__float_as_uint(a) & 0xFFFF0000u);
  float rb = b - __uint_as_float(__float_as_uint(b) & 0xFFFF0000u);
  return (__float_as_uint(ra) >> 16) | (__float_as_uint(rb) & 0xFFFF0000u);
}

// stage 16 consecutive fp32 into LDS as 16 hi-bf16 + 16 lo-bf16.
__device__ __forceinline__ void stage16(const float* __restrict__ p,
                                        u16* dhi, u16* dlo) {
  float4 a0 = *(const float4*)p;
  float4 a1 = *(const float4*)(p + 4);
  float4 a2 = *(const float4*)(p + 8);
  float4 a3 = *(const float4*)(p + 12);
  uint4 h0 = {pack_hi2(a0.x, a0.y), pack_hi2(a0.z, a0.w),
              pack_hi2(a1.x, a1.y), pack_hi2(a1.z, a1.w)};
  uint4 h1 = {pack_hi2(a2.x, a2.y), pack_hi2(a2.z, a2.w),
              pack_hi2(a3.x, a3.y), pack_hi2(a3.z, a3.w)};
  uint4 l0 = {pack_lo2(a0.x, a0.y), pack_lo2(a0.z, a0.w),
              pack_lo2(a1.x, a1.y), pack_lo2(a1.z, a1.w)};
  uint4 l1 = {pack_lo2(a2.x, a2.y), pack_lo2(a2.z, a2.w),
              pack_lo2(a3.x, a3.y), pack_lo2(a3.z, a3.w)};
  *(uint4*)dhi = h0;
  *(uint4*)(dhi + 8) = h1;
  *(uint4*)dlo = l0;
  *(uint4*)(dlo + 8) = l1;
}

// ---------------------------------------------------------------------------
// K1: s[b,i,j] = cwc[i] + qwq[j] + sum_h c[i,h]*w_cq[h]*q[j,h], softmax over i
// per column j.  Writes s1 twice:
//   s1ws[b][j][i]        bf16  (B-operand for K2: rows j, K = i)
//   s1tb[b][jgrp][i][8]  bf16  (fragment-blocked transpose for K3's direct
//                               global B-frag loads: jgrp = j>>3)
// Grid (b, jgroup): blockIdx.x = b so the 8 j-blocks sharing ctx[b] land on
// the same XCD (linear id % 8 == b % 8) -> ctx read from L2, not HBM 8x.
// ---------------------------------------------------------------------------
__global__ __launch_bounds__(512) void k1_s_softmax(
    const float* __restrict__ ctx, const float* __restrict__ qst,
    const float* __restrict__ w, u16* __restrict__ s1ws,
    u16* __restrict__ s1tb) {
  const int b = blockIdx.x;
  const int j0 = blockIdx.y * 16;
  const int tid = threadIdx.x;
  const float* cb = ctx + (size_t)b * HH * CC;
  const float* qb = qst + (size_t)b * HH * QQ;

  float dotv[16][2];
  float qwq[16];
  float cwc[2] = {0.f, 0.f};
#pragma unroll
  for (int jj = 0; jj < 16; ++jj) {
    qwq[jj] = 0.f;
    dotv[jj][0] = dotv[jj][1] = 0.f;
  }

  for (int h = 0; h < HH; ++h) {
    const float2 cv = *(const float2*)(cb + (size_t)h * CC + tid * 2);
    float c0 = cv.x, c1 = cv.y;
    float wqv = w[h], wcv = w[HH + h], wcqv = w[2 * HH + h];
    cwc[0] += c0 * wcv; cwc[1] += c1 * wcv;
    float t0 = c0 * wcqv, t1 = c1 * wcqv;
    const float4* qrow = (const float4*)(qb + (size_t)h * QQ + j0);
    float4 q0 = qrow[0], q1 = qrow[1], q2 = qrow[2], q3 = qrow[3];
    float qv[16] = {q0.x, q0.y, q0.z, q0.w, q1.x, q1.y, q1.z, q1.w,
                    q2.x, q2.y, q2.z, q2.w, q3.x, q3.y, q3.z, q3.w};
#pragma unroll
    for (int jj = 0; jj < 16; ++jj) {
      qwq[jj] += qv[jj] * wqv;
      dotv[jj][0] += t0 * qv[jj];
      dotv[jj][1] += t1 * qv[jj];
    }
  }
#pragma unroll
  for (int jj = 0; jj < 16; ++jj) {
    float base = qwq[jj];
    dotv[jj][0] += cwc[0] + base;
    dotv[jj][1] += cwc[1] + base;
  }

  __shared__ float red[16 * 512];
  __shared__ float red2[16 * 32];
  __shared__ float bc[16];
  const int rj = tid >> 5, rs = tid & 31;

  // ---- max over i per column jj ----
#pragma unroll
  for (int jj = 0; jj < 16; ++jj)
    red[jj * 512 + tid] = fmaxf(dotv[jj][0], dotv[jj][1]);
  __syncthreads();
  {
    float m = red[rj * 512 + rs * 16];
#pragma unroll
    for (int g = 1; g < 16; ++g) m = fmaxf(m, red[rj * 512 + rs * 16 + g]);
    red2[rj * 32 + rs] = m;
  }
  __syncthreads();
  if (tid < 16) {
    float m = red2[tid * 32];
#pragma unroll
    for (int g = 1; g < 32; ++g) m = fmaxf(m, red2[tid * 32 + g]);
    bc[tid] = m;
  }
  __syncthreads();

  // ---- exp + sum ----
#pragma unroll
  for (int jj = 0; jj < 16; ++jj) {
    float mj = bc[jj];
    float e0 = __expf(dotv[jj][0] - mj);
    float e1 = __expf(dotv[jj][1] - mj);
    dotv[jj][0] = e0; dotv[jj][1] = e1;
    red[jj * 512 + tid] = e0 + e1;
  }
  __syncthreads();
  {
    float s = 0.f;
#pragma unroll
    for (int g = 0; g < 16; ++g) s += red[rj * 512 + rs * 16 + g];
    red2[rj * 32 + rs] = s;
  }
  __syncthreads();
  if (tid < 16) {
    float s = 0.f;
#pragma unroll
    for (int g = 0; g < 32; ++g) s += red2[tid * 32 + g];
    bc[tid] = 1.0f / s;
  }
  __syncthreads();

  // ---- normalize in place, then write both layouts ----
#pragma unroll
  for (int jj = 0; jj < 16; ++jj) {
    float inv = bc[jj];
    dotv[jj][0] *= inv;
    dotv[jj][1] *= inv;
  }
  u16* srow = s1ws + ((size_t)b * QQ + j0) * CC + tid * 2;
#pragma unroll
  for (int jj = 0; jj < 16; ++jj) {
    u32 pk = (u32)f2b(dotv[jj][0]) | ((u32)f2b(dotv[jj][1]) << 16);
    *(u32*)(srow + (size_t)jj * CC) = pk;
  }
  // blocked transpose: element (i, j) at s1tb[((j>>3)*1024 + i)*8 + (j&7)].
  u16* stb = s1tb + (size_t)b * (16 * 1024 * 8);
  const int jg0 = j0 >> 3;
#pragma unroll
  for (int g = 0; g < 2; ++g) {
#pragma unroll
    for (int rr = 0; rr < 2; ++rr) {
      const int o = g * 8;
      uint4 v;
      v.x = (u32)f2b(dotv[o + 0][rr]) | ((u32)f2b(dotv[o + 1][rr]) << 16);
      v.y = (u32)f2b(dotv[o + 2][rr]) | ((u32)f2b(dotv[o + 3][rr]) << 16);
      v.z = (u32)f2b(dotv[o + 4][rr]) | ((u32)f2b(dotv[o + 5][rr]) << 16);
      v.w = (u32)f2b(dotv[o + 6][rr]) | ((u32)f2b(dotv[o + 7][rr]) << 16);
      *(uint4*)(stb + ((size_t)(jg0 + g) * 1024 + (tid * 2 + rr)) * 8) = v;
    }
  }
}

// ---------------------------------------------------------------------------
// K2 (MFMA, no split-K, no atomics): tT[b][h][j] = sum_i s1[i,j] c[i,h]
//   A = ctx rows h (hi+lo bf16, LDS-staged per 128-i slice)
//   B = s1ws rows j (bf16, direct-global frags; 64B-contiguous per row)
// Grid (b, 8): blockIdx.y = (h_quarter << 1) | j_half; block = 32h x 64j,
// full K=1024.  Each wave: 2 h-tiles x 1 j-tile.  Plain coalesced stores.
// 8 blocks/b cover all 128h x 128j.
// ---------------------------------------------------------------------------
__global__ __launch_bounds__(256) void k2_t(
    const float* __restrict__ ctx, const u16* __restrict__ s1ws,
    float* __restrict__ tT) {
  const int b = blockIdx.x;
  const int h0 = (blockIdx.y >> 1) * 32;   // 0,32,64,96
  const int j0 = (blockIdx.y & 1) * 64;    // 0,64
  const int tid = threadIdx.x;
  const int lane = tid & 63;
  const int wv = tid >> 6;
  const int l15 = lane & 15, l4 = lane >> 4;

  __shared__ u16 sHi[32 * 136];   // 136-pitch: 2-way banks on frag reads
  __shared__ u16 sLo[32 * 136];

  f32x4 acc[2];
  acc[0] = 0.f; acc[1] = 0.f;

  const float* cb = ctx + ((size_t)b * HH + h0) * CC;
  const u16* sb = s1ws + ((size_t)b * QQ + j0 + wv * 16 + l15) * CC;
  const int srow = tid >> 3;         // 0..31
  const int scol = (tid & 7) * 16;   // 0..112

  for (int k0 = 0; k0 < CC; k0 += 128) {
    __syncthreads();
    stage16(cb + (size_t)srow * CC + k0 + scol,
            &sHi[srow * 136 + scol], &sLo[srow * 136 + scol]);
    __syncthreads();
#pragma unroll
    for (int kk = 0; kk < 4; ++kk) {
      bf16x8 bf = *(const bf16x8*)(sb + k0 + kk * 32 + l4 * 8);
#pragma unroll
      for (int ht = 0; ht < 2; ++ht) {
        const int ar = (ht * 16 + l15) * 136 + kk * 32 + l4 * 8;
        bf16x8 ah = *(const bf16x8*)&sHi[ar];
        bf16x8 al = *(const bf16x8*)&sLo[ar];
        acc[ht] = MFMA16(ah, bf, acc[ht]);
        acc[ht] = MFMA16(al, bf, acc[ht]);
      }
    }
  }
  // D: col (lane&15) = j, row = (lane>>4)*4 + r = h within tile.
  float* tb = tT + (size_t)b * HH * QQ;
#pragma unroll
  for (int ht = 0; ht < 2; ++ht)
#pragma unroll
    for (int r = 0; r < 4; ++r)
      tb[(size_t)(h0 + ht * 16 + l4 * 4 + r) * QQ + j0 + wv * 16 + l15] =
          acc[ht][r];
}

// ---------------------------------------------------------------------------
// K3 (MFMA): a[i,h] = sum_j s1[i,j] q[j,h];  bb[i,h] = sum_j s1[i,j] t[j,h]
//   A = qst[h][j] and tT[h][j] (hi+lo bf16, LDS-staged per 32-j slice)
//   B = s1tb blocked frags (bf16, direct-global; free = i, K = j)
// Operand order chosen so D's lane-fast dim is i -> coalesced output stores
// (16 lanes = 64B contiguous).  Epilogue fuses c / a / c*a / c*b.
// ---------------------------------------------------------------------------
__global__ __launch_bounds__(256, 2) void k3_out(
    const float* __restrict__ ctx, const float* __restrict__ qst,
    const u16* __restrict__ s1tb, const float* __restrict__ tT,
    float* __restrict__ out) {
  const int b = blockIdx.x;
  const int i0 = blockIdx.y * 128;
  const int tid = threadIdx.x;
  const int lane = tid & 63;
  const int wv = tid >> 6;
  const int l15 = lane & 15, l4 = lane >> 4;

  __shared__ u16 qHi[128 * 40], qLo[128 * 40];   // 40-pitch: 2-way banks
  __shared__ u16 tHi[128 * 40], tLo[128 * 40];

  f32x4 accA[8][2], accB[8][2];
#pragma unroll
  for (int it = 0; it < 8; ++it)
#pragma unroll
    for (int ht = 0; ht < 2; ++ht) { accA[it][ht] = 0.f; accB[it][ht] = 0.f; }

  const u16* stb = s1tb + (size_t)b * (16 * 1024 * 8);
  const float* qb = qst + (size_t)b * HH * QQ;
  const float* tb = tT + (size_t)b * HH * QQ;
  const int srow = tid >> 1;        // 0..127
  const int scol = (tid & 1) * 16;  // 0,16

  for (int ks = 0; ks < 4; ++ks) {
    const int jb = ks * 32;
    __syncthreads();
    stage16(qb + (size_t)srow * QQ + jb + scol,
            &qHi[srow * 40 + scol], &qLo[srow * 40 + scol]);
    stage16(tb + (size_t)srow * QQ + jb + scol,
            &tHi[srow * 40 + scol], &tLo[srow * 40 + scol]);
    __syncthreads();
    bf16x8 qh[2], ql[2], th[2], tl[2];
#pragma unroll
    for (int ht = 0; ht < 2; ++ht) {
      const int ar = (wv * 32 + ht * 16 + l15) * 40 + l4 * 8;
      qh[ht] = *(const bf16x8*)&qHi[ar];
      ql[ht] = *(const bf16x8*)&qLo[ar];
      th[ht] = *(const bf16x8*)&tHi[ar];
      tl[ht] = *(const bf16x8*)&tLo[ar];
    }
    // B-frags (s1) direct from global (blocked layout), 2 halves to cap VGPRs.
#pragma unroll
    for (int half = 0; half < 2; ++half) {
      bf16x8 bfr[4];
#pragma unroll
      for (int t4 = 0; t4 < 4; ++t4) {
        const int it = half * 4 + t4;
        bfr[t4] = *(const bf16x8*)(stb +
            ((size_t)(ks * 4 + l4) * 1024 + i0 + it * 16 + l15) * 8);
      }
#pragma unroll
      for (int t4 = 0; t4 < 4; ++t4) {
        const int it = half * 4 + t4;
#pragma unroll
        for (int ht = 0; ht < 2; ++ht) {
          accA[it][ht] = MFMA16(qh[ht], bfr[t4], accA[it][ht]);
          accA[it][ht] = MFMA16(ql[ht], bfr[t4], accA[it][ht]);
          accB[it][ht] = MFMA16(th[ht], bfr[t4], accB[it][ht]);
          accB[it][ht] = MFMA16(tl[ht], bfr[t4], accB[it][ht]);
        }
      }
    }
  }

  // Epilogue: D col (lane&15) = i, row = (lane>>4)*4 + r = h.
  // 16 lanes store 64B contiguous -> full cachelines.
  const float* cb = ctx + (size_t)b * HH * CC;
  float* ob = out + (size_t)b * 4 * HH * CC;
#pragma unroll
  for (int it = 0; it < 8; ++it) {
    const int ii = i0 + it * 16 + l15;
#pragma unroll
    for (int ht = 0; ht < 2; ++ht) {
#pragma unroll
      for (int r = 0; r < 4; ++r) {
        const int h = wv * 32 + ht * 16 + l4 * 4 + r;
        const size_t base = (size_t)h * CC + ii;
        const float cv = cb[base];
        const float av = accA[it][ht][r];
        const float bv = accB[it][ht][r];
        ob[base] = cv;
        ob[(size_t)HH * CC + base] = av;
        ob[(size_t)2 * HH * CC + base] = cv * av;
        ob[(size_t)3 * HH * CC + base] = cv * bv;
      }
    }
  }
}

extern "C" void kernel_launch(void* const* d_in, const int* in_sizes, int n_in,
                              void* d_out, int out_size, void* d_ws, size_t ws_size,
                              hipStream_t stream) {
  const float* ctx = (const float*)d_in[0];
  const float* qst = (const float*)d_in[1];
  const float* w = (const float*)d_in[2];
  for (int k = 0; k < n_in; ++k) {
    if (in_sizes[k] == BB * HH * CC) ctx = (const float*)d_in[k];
    else if (in_sizes[k] == BB * HH * QQ) qst = (const float*)d_in[k];
    else if (in_sizes[k] == 3 * HH) w = (const float*)d_in[k];
  }
  float* out = (float*)d_out;

  // Workspace: s1ws bf16 (16 MiB) + s1tb bf16 (16 MiB) + tT fp32 (4 MiB).
  u16* s1ws = (u16*)d_ws;
  u16* s1tb = (u16*)((char*)d_ws + (size_t)16 * 1024 * 1024);
  float* tT = (float*)((char*)d_ws + (size_t)32 * 1024 * 1024);

  k1_s_softmax<<<dim3(BB, QQ / 16), 512, 0, stream>>>(ctx, qst, w, s1ws, s1tb);
  k2_t<<<dim3(BB, 8), 256, 0, stream>>>(ctx, s1ws, tT);
  k3_out<<<dim3(BB, 8), 256, 0, stream>>>(ctx, qst, s1tb, tT, out);
}

// Round 4
// 245.666 us; speedup vs baseline: 1.2377x; 1.0214x over previous
//
#include <hip/hip_runtime.h>

#define BB 64
#define HH 128
#define CC 1024
#define QQ 128

typedef unsigned short u16;
typedef unsigned int u32;
using bf16x8 = __attribute__((ext_vector_type(8))) short;
using f32x4 = __attribute__((ext_vector_type(4))) float;

#define MFMA16(a, b, c) __builtin_amdgcn_mfma_f32_16x16x32_bf16(a, b, c, 0, 0, 0)

__device__ __forceinline__ u16 f2b(float f) {
  union { float f; u32 i; } v; v.f = f;
  u32 r = v.i + 0x7FFFu + ((v.i >> 16) & 1u);   // RNE
  return (u16)(r >> 16);
}
// Dekker hi/lo split packers: x = hi + lo + eps, |eps| <= 2^-17 |x|
__device__ __forceinline__ u32 pack_hi2(float a, float b) {
  return (__float_as_uint(a) >> 16) | (__float_as_uint(b) & 0xFFFF0000u);
}
__device__ __forceinline__ u32 pack_lo2(float a, float b) {
  float ra = a - __uint_as_float(__float_as_uint(a) & 0xFFFF0000u);
  float rb = b - __uint_as_float(__float_as_uint(b) & 0xFFFF0000u);
  return (__float_as_uint(ra) >> 16) | (__float_as_uint(rb) & 0xFFFF0000u);
}

// stage 16 consecutive fp32 into LDS as 16 hi-bf16 + 16 lo-bf16 (k2/k3).
__device__ __forceinline__ void stage16(const float* __restrict__ p,
                                        u16* dhi, u16* dlo) {
  float4 a0 = *(const float4*)p;
  float4 a1 = *(const float4*)(p + 4);
  float4 a2 = *(const float4*)(p + 8);
  float4 a3 = *(const float4*)(p + 12);
  uint4 h0 = {pack_hi2(a0.x, a0.y), pack_hi2(a0.z, a0.w),
              pack_hi2(a1.x, a1.y), pack_hi2(a1.z, a1.w)};
  uint4 h1 = {pack_hi2(a2.x, a2.y), pack_hi2(a2.z, a2.w),
              pack_hi2(a3.x, a3.y), pack_hi2(a3.z, a3.w)};
  uint4 l0 = {pack_lo2(a0.x, a0.y), pack_lo2(a0.z, a0.w),
              pack_lo2(a1.x, a1.y), pack_lo2(a1.z, a1.w)};
  uint4 l1 = {pack_lo2(a2.x, a2.y), pack_lo2(a2.z, a2.w),
              pack_lo2(a3.x, a3.y), pack_lo2(a3.z, a3.w)};
  *(uint4*)dhi = h0;
  *(uint4*)(dhi + 8) = h1;
  *(uint4*)dlo = l0;
  *(uint4*)(dlo + 8) = l1;
}

// ---------------------------------------------------------------------------
// k_qw: qw[b][j][h] (144 rows, hi+lo bf16):
//   rows 0..127 : q[b][j][h] * w_cq[h]   (w folded into the small operand)
//   row  128    : w_c[h]                  (aux row -> MFMA computes cwc[i])
//   rows 129..143: 0                      (tile padding)
// LDS transpose of qst[b] (row-major [h][j]) with pitch 129 (conflict-free
// column reads).
// ---------------------------------------------------------------------------
__global__ __launch_bounds__(256) void k_qw(
    const float* __restrict__ qst, const float* __restrict__ w,
    u16* __restrict__ qwh, u16* __restrict__ qwl) {
  const int b = blockIdx.x;
  const int tid = threadIdx.x;
  __shared__ float ld[128 * 129];
  __shared__ float wcq[128];
  const float* qb = qst + (size_t)b * HH * QQ;
#pragma unroll
  for (int rep = 0; rep < 16; ++rep) {
    int h = rep * 8 + (tid >> 5);
    int jo = (tid & 31) * 4;
    float4 v = *(const float4*)(qb + (size_t)h * QQ + jo);
    float* d = &ld[h * 129 + jo];
    d[0] = v.x; d[1] = v.y; d[2] = v.z; d[3] = v.w;
  }
  if (tid < 128) wcq[tid] = w[2 * HH + tid];
  __syncthreads();
  const int j = tid >> 1;
  const int hh0 = (tid & 1) * 64;
  u16* oh = qwh + (size_t)b * 144 * 128 + j * 128 + hh0;
  u16* ol = qwl + (size_t)b * 144 * 128 + j * 128 + hh0;
#pragma unroll
  for (int g = 0; g < 8; ++g) {
    u32 hw[4], lw[4];
#pragma unroll
    for (int p = 0; p < 4; ++p) {
      int h = hh0 + g * 8 + p * 2;
      float a = ld[h * 129 + j] * wcq[h];
      float c = ld[(h + 1) * 129 + j] * wcq[h + 1];
      hw[p] = pack_hi2(a, c);
      lw[p] = pack_lo2(a, c);
    }
    uint4 vh = {hw[0], hw[1], hw[2], hw[3]};
    uint4 vl = {lw[0], lw[1], lw[2], lw[3]};
    *(uint4*)(oh + g * 8) = vh;
    *(uint4*)(ol + g * 8) = vl;
  }
  // aux rows 128..143 (16 rows x 8 threads x 16 h each)
  if (tid < 128) {
    int jr = 128 + (tid >> 3);
    int hc = (tid & 7) * 16;
    u32 hw[8], lw[8];
#pragma unroll
    for (int p = 0; p < 8; ++p) { hw[p] = 0; lw[p] = 0; }
    if (jr == 128) {
#pragma unroll
      for (int p = 0; p < 8; ++p) {
        float a = w[HH + hc + p * 2];
        float c = w[HH + hc + p * 2 + 1];
        hw[p] = pack_hi2(a, c);
        lw[p] = pack_lo2(a, c);
      }
    }
    u16* ph = qwh + (size_t)b * 144 * 128 + (size_t)jr * 128 + hc;
    u16* pl = qwl + (size_t)b * 144 * 128 + (size_t)jr * 128 + hc;
    uint4 vh0 = {hw[0], hw[1], hw[2], hw[3]};
    uint4 vh1 = {hw[4], hw[5], hw[6], hw[7]};
    uint4 vl0 = {lw[0], lw[1], lw[2], lw[3]};
    uint4 vl1 = {lw[4], lw[5], lw[6], lw[7]};
    *(uint4*)ph = vh0; *(uint4*)(ph + 8) = vh1;
    *(uint4*)pl = vl0; *(uint4*)(pl + 8) = vl1;
  }
}

// ---------------------------------------------------------------------------
// k_ct: cTh[b][i][h] = bf16_hi(ctx[b][h][i])  -- plain c, transposed, hi only.
// (c-lo term dropped: adds ~1e-3 abs on s, far under the bf16-s1 rounding.)
// Grid (b, i-chunk of 128).  LDS transpose with pitch 129.
// ---------------------------------------------------------------------------
__global__ __launch_bounds__(256) void k_ct(
    const float* __restrict__ ctx, u16* __restrict__ cTh) {
  const int b = blockIdx.x;
  const int i0 = blockIdx.y * 128;
  const int tid = threadIdx.x;
  __shared__ float ld[128 * 129];
  const float* cb = ctx + (size_t)b * HH * CC;
#pragma unroll
  for (int rep = 0; rep < 16; ++rep) {
    int h = rep * 8 + (tid >> 5);
    int io = (tid & 31) * 4;
    float4 v = *(const float4*)(cb + (size_t)h * CC + i0 + io);
    float* d = &ld[h * 129 + io];
    d[0] = v.x; d[1] = v.y; d[2] = v.z; d[3] = v.w;
  }
  __syncthreads();
  const int i = tid >> 1;
  const int hh0 = (tid & 1) * 64;
  u16* oh = cTh + (size_t)b * CC * HH + (size_t)(i0 + i) * 128 + hh0;
#pragma unroll
  for (int g = 0; g < 8; ++g) {
    u32 hw[4];
#pragma unroll
    for (int p = 0; p < 4; ++p) {
      int h = hh0 + g * 8 + p * 2;
      hw[p] = pack_hi2(ld[h * 129 + i], ld[(h + 1) * 129 + i]);
    }
    uint4 vh = {hw[0], hw[1], hw[2], hw[3]};
    *(uint4*)(oh + g * 8) = vh;
  }
}

// ---------------------------------------------------------------------------
// k0_softmax: s[j][i] = cwc[i] + sum_h qw[j][h] c[i][h]   (qwq[j] cancels in
// the softmax over i and is dropped).  MFMA: A = qw frags (row=j), B = cT
// frags (col=i); aux A-row 128 (= w_c) yields cwc[i] in D row 0 of the aux
// tile.  Softmax over i fully in registers: reduce over it-tiles + shfl_xor
// over l15 + tiny LDS cross-wave combine.  Writes s1ws + s1tb.
// Grid (b, j-tile of 16) = 512 blocks, 512 thr (8 waves x 128 i each).
// ---------------------------------------------------------------------------
__global__ __launch_bounds__(512) void k0_softmax(
    const u16* __restrict__ cTh, const u16* __restrict__ qwh,
    const u16* __restrict__ qwl, u16* __restrict__ s1ws,
    u16* __restrict__ s1tb) {
  const int b = blockIdx.x;
  const int j0 = blockIdx.y * 16;
  const int tid = threadIdx.x;
  const int lane = tid & 63;
  const int wv = tid >> 6;
  const int l15 = lane & 15, l4 = lane >> 4;
  __shared__ float wred[2][8][4][4];

  const u16* cb = cTh + (size_t)b * CC * HH;
  const u16* qhp = qwh + (size_t)b * 144 * 128;
  const u16* qlp = qwl + (size_t)b * 144 * 128;

  // A-frag cache (loop-invariant): real j-tile hi+lo, aux tile hi.
  bf16x8 aqh[4], aql[4], axh[4];
#pragma unroll
  for (int kk = 0; kk < 4; ++kk) {
    const int off = kk * 32 + l4 * 8;
    aqh[kk] = *(const bf16x8*)(qhp + (size_t)(j0 + l15) * 128 + off);
    aql[kk] = *(const bf16x8*)(qlp + (size_t)(j0 + l15) * 128 + off);
    axh[kk] = *(const bf16x8*)(qhp + (size_t)(128 + l15) * 128 + off);
  }

  f32x4 sv[8];
  float cwcv[8];
#pragma unroll
  for (int it = 0; it < 8; ++it) {
    const int i = wv * 128 + it * 16 + l15;
    f32x4 aR = {0.f, 0.f, 0.f, 0.f};
    f32x4 aX = {0.f, 0.f, 0.f, 0.f};
#pragma unroll
    for (int kk = 0; kk < 4; ++kk) {
      bf16x8 bh = *(const bf16x8*)(cb + (size_t)i * 128 + kk * 32 + l4 * 8);
      aR = MFMA16(aqh[kk], bh, aR);
      aR = MFMA16(aql[kk], bh, aR);
      aX = MFMA16(axh[kk], bh, aX);
    }
    // aux D row 0 (l4==0, reg 0) = cwc[i]; broadcast across l4 groups.
    cwcv[it] = __shfl(aX[0], l15);
    sv[it] = aR;
  }
#pragma unroll
  for (int it = 0; it < 8; ++it)
#pragma unroll
    for (int r = 0; r < 4; ++r) sv[it][r] += cwcv[it];

  // ---- max over i (this wave's 128 i), per j = j0 + l4*4 + r ----
  float mj[4];
#pragma unroll
  for (int r = 0; r < 4; ++r) {
    float m = sv[0][r];
#pragma unroll
    for (int it = 1; it < 8; ++it) m = fmaxf(m, sv[it][r]);
#pragma unroll
    for (int msk = 1; msk < 16; msk <<= 1) m = fmaxf(m, __shfl_xor(m, msk));
    mj[r] = m;
  }
  if (l15 == 0) {
#pragma unroll
    for (int r = 0; r < 4; ++r) wred[0][wv][l4][r] = mj[r];
  }
  __syncthreads();
  float gm[4];
#pragma unroll
  for (int r = 0; r < 4; ++r) {
    float m = wred[0][0][l4][r];
#pragma unroll
    for (int w2 = 1; w2 < 8; ++w2) m = fmaxf(m, wred[0][w2][l4][r]);
    gm[r] = m;
  }

  // ---- exp + sum ----
#pragma unroll
  for (int it = 0; it < 8; ++it)
#pragma unroll
    for (int r = 0; r < 4; ++r) sv[it][r] = __expf(sv[it][r] - gm[r]);
  float sj[4];
#pragma unroll
  for (int r = 0; r < 4; ++r) {
    float s = 0.f;
#pragma unroll
    for (int it = 0; it < 8; ++it) s += sv[it][r];
#pragma unroll
    for (int msk = 1; msk < 16; msk <<= 1) s += __shfl_xor(s, msk);
    sj[r] = s;
  }
  if (l15 == 0) {
#pragma unroll
    for (int r = 0; r < 4; ++r) wred[1][wv][l4][r] = sj[r];
  }
  __syncthreads();
  float inv_[4];
#pragma unroll
  for (int r = 0; r < 4; ++r) {
    float s = 0.f;
#pragma unroll
    for (int w2 = 0; w2 < 8; ++w2) s += wred[1][w2][l4][r];
    inv_[r] = 1.0f / s;
  }

  // ---- write both s1 layouts ----
  u16* ws = s1ws + (size_t)b * QQ * CC;
  u16* tb = s1tb + (size_t)b * (16 * 1024 * 8);
#pragma unroll
  for (int it = 0; it < 8; ++it) {
    const int i = wv * 128 + it * 16 + l15;
#pragma unroll
    for (int r = 0; r < 4; ++r) {
      const int j = j0 + l4 * 4 + r;
      u16 pv = f2b(sv[it][r] * inv_[r]);
      ws[(size_t)j * CC + i] = pv;
      tb[((size_t)(j >> 3) * 1024 + i) * 8 + (j & 7)] = pv;
    }
  }
}

// ---------------------------------------------------------------------------
// K2 (MFMA): tT[b][h][j] = sum_i s1[i,j] c[i,h]
// ---------------------------------------------------------------------------
__global__ __launch_bounds__(256) void k2_t(
    const float* __restrict__ ctx, const u16* __restrict__ s1ws,
    float* __restrict__ tT) {
  const int b = blockIdx.x;
  const int h0 = (blockIdx.y >> 1) * 32;   // 0,32,64,96
  const int j0 = (blockIdx.y & 1) * 64;    // 0,64
  const int tid = threadIdx.x;
  const int lane = tid & 63;
  const int wv = tid >> 6;
  const int l15 = lane & 15, l4 = lane >> 4;

  __shared__ u16 sHi[32 * 136];
  __shared__ u16 sLo[32 * 136];

  f32x4 acc[2];
  acc[0] = 0.f; acc[1] = 0.f;

  const float* cb = ctx + ((size_t)b * HH + h0) * CC;
  const u16* sb = s1ws + ((size_t)b * QQ + j0 + wv * 16 + l15) * CC;
  const int srow = tid >> 3;
  const int scol = (tid & 7) * 16;

  for (int k0 = 0; k0 < CC; k0 += 128) {
    __syncthreads();
    stage16(cb + (size_t)srow * CC + k0 + scol,
            &sHi[srow * 136 + scol], &sLo[srow * 136 + scol]);
    __syncthreads();
#pragma unroll
    for (int kk = 0; kk < 4; ++kk) {
      bf16x8 bf = *(const bf16x8*)(sb + k0 + kk * 32 + l4 * 8);
#pragma unroll
      for (int ht = 0; ht < 2; ++ht) {
        const int ar = (ht * 16 + l15) * 136 + kk * 32 + l4 * 8;
        bf16x8 ah = *(const bf16x8*)&sHi[ar];
        bf16x8 al = *(const bf16x8*)&sLo[ar];
        acc[ht] = MFMA16(ah, bf, acc[ht]);
        acc[ht] = MFMA16(al, bf, acc[ht]);
      }
    }
  }
  float* tb = tT + (size_t)b * HH * QQ;
#pragma unroll
  for (int ht = 0; ht < 2; ++ht)
#pragma unroll
    for (int r = 0; r < 4; ++r)
      tb[(size_t)(h0 + ht * 16 + l4 * 4 + r) * QQ + j0 + wv * 16 + l15] =
          acc[ht][r];
}

// ---------------------------------------------------------------------------
// K3 (MFMA): a[i,h] = sum_j s1[i,j] q[j,h];  bb[i,h] = sum_j s1[i,j] t[j,h]
// ---------------------------------------------------------------------------
__global__ __launch_bounds__(256, 2) void k3_out(
    const float* __restrict__ ctx, const float* __restrict__ qst,
    const u16* __restrict__ s1tb, const float* __restrict__ tT,
    float* __restrict__ out) {
  const int b = blockIdx.x;
  const int i0 = blockIdx.y * 128;
  const int tid = threadIdx.x;
  const int lane = tid & 63;
  const int wv = tid >> 6;
  const int l15 = lane & 15, l4 = lane >> 4;

  __shared__ u16 qHi[128 * 40], qLo[128 * 40];
  __shared__ u16 tHi[128 * 40], tLo[128 * 40];

  f32x4 accA[8][2], accB[8][2];
#pragma unroll
  for (int it = 0; it < 8; ++it)
#pragma unroll
    for (int ht = 0; ht < 2; ++ht) { accA[it][ht] = 0.f; accB[it][ht] = 0.f; }

  const u16* stb = s1tb + (size_t)b * (16 * 1024 * 8);
  const float* qb = qst + (size_t)b * HH * QQ;
  const float* tb = tT + (size_t)b * HH * QQ;
  const int srow = tid >> 1;
  const int scol = (tid & 1) * 16;

  for (int ks = 0; ks < 4; ++ks) {
    const int jb = ks * 32;
    __syncthreads();
    stage16(qb + (size_t)srow * QQ + jb + scol,
            &qHi[srow * 40 + scol], &qLo[srow * 40 + scol]);
    stage16(tb + (size_t)srow * QQ + jb + scol,
            &tHi[srow * 40 + scol], &tLo[srow * 40 + scol]);
    __syncthreads();
    bf16x8 qh[2], ql[2], th[2], tl[2];
#pragma unroll
    for (int ht = 0; ht < 2; ++ht) {
      const int ar = (wv * 32 + ht * 16 + l15) * 40 + l4 * 8;
      qh[ht] = *(const bf16x8*)&qHi[ar];
      ql[ht] = *(const bf16x8*)&qLo[ar];
      th[ht] = *(const bf16x8*)&tHi[ar];
      tl[ht] = *(const bf16x8*)&tLo[ar];
    }
#pragma unroll
    for (int half = 0; half < 2; ++half) {
      bf16x8 bfr[4];
#pragma unroll
      for (int t4 = 0; t4 < 4; ++t4) {
        const int it = half * 4 + t4;
        bfr[t4] = *(const bf16x8*)(stb +
            ((size_t)(ks * 4 + l4) * 1024 + i0 + it * 16 + l15) * 8);
      }
#pragma unroll
      for (int t4 = 0; t4 < 4; ++t4) {
        const int it = half * 4 + t4;
#pragma unroll
        for (int ht = 0; ht < 2; ++ht) {
          accA[it][ht] = MFMA16(qh[ht], bfr[t4], accA[it][ht]);
          accA[it][ht] = MFMA16(ql[ht], bfr[t4], accA[it][ht]);
          accB[it][ht] = MFMA16(th[ht], bfr[t4], accB[it][ht]);
          accB[it][ht] = MFMA16(tl[ht], bfr[t4], accB[it][ht]);
        }
      }
    }
  }

  const float* cb = ctx + (size_t)b * HH * CC;
  float* ob = out + (size_t)b * 4 * HH * CC;
#pragma unroll
  for (int it = 0; it < 8; ++it) {
    const int ii = i0 + it * 16 + l15;
#pragma unroll
    for (int ht = 0; ht < 2; ++ht) {
#pragma unroll
      for (int r = 0; r < 4; ++r) {
        const int h = wv * 32 + ht * 16 + l4 * 4 + r;
        const size_t base = (size_t)h * CC + ii;
        const float cv = cb[base];
        const float av = accA[it][ht][r];
        const float bv = accB[it][ht][r];
        ob[base] = cv;
        ob[(size_t)HH * CC + base] = av;
        ob[(size_t)2 * HH * CC + base] = cv * av;
        ob[(size_t)3 * HH * CC + base] = cv * bv;
      }
    }
  }
}

extern "C" void kernel_launch(void* const* d_in, const int* in_sizes, int n_in,
                              void* d_out, int out_size, void* d_ws, size_t ws_size,
                              hipStream_t stream) {
  const float* ctx = (const float*)d_in[0];
  const float* qst = (const float*)d_in[1];
  const float* w = (const float*)d_in[2];
  for (int k = 0; k < n_in; ++k) {
    if (in_sizes[k] == BB * HH * CC) ctx = (const float*)d_in[k];
    else if (in_sizes[k] == BB * HH * QQ) qst = (const float*)d_in[k];
    else if (in_sizes[k] == 3 * HH) w = (const float*)d_in[k];
  }
  float* out = (float*)d_out;

  // Workspace (36 MiB, proven): s1ws bf16 + s1tb bf16 + tT fp32.
  u16* s1ws = (u16*)d_ws;
  u16* s1tb = (u16*)((char*)d_ws + (size_t)16 * 1024 * 1024);
  float* tT = (float*)((char*)d_ws + (size_t)32 * 1024 * 1024);

  // Scratch for qw/cT lives in the TAIL of out (128 MiB): dead by the time
  // k3 (which overwrites every byte of out) runs.  out is zeroed by the
  // harness before each launch; we write scratch before reading it.
  char* ob = (char*)d_out;
  u16* qwl = (u16*)(ob + 112721920);   // 2,359,296 B
  u16* qwh = (u16*)(ob + 115081216);   // 2,359,296 B
  u16* cTh = (u16*)(ob + 117440512);   // 16,777,216 B -> ends at 134,217,728

  k_qw<<<BB, 256, 0, stream>>>(qst, w, qwh, qwl);
  k_ct<<<dim3(BB, 8), 256, 0, stream>>>(ctx, cTh);
  k0_softmax<<<dim3(BB, 8), 512, 0, stream>>>(cTh, qwh, qwl, s1ws, s1tb);
  k2_t<<<dim3(BB, 8), 256, 0, stream>>>(ctx, s1ws, tT);
  k3_out<<<dim3(BB, 8), 256, 0, stream>>>(ctx, qst, s1tb, tT, out);
}